// Round 12
// baseline (308.702 us; speedup 1.0000x reference)
//
#include <hip/hip_runtime.h>
#include <cstddef>

#define BATCH 64
#define FD    256
#define SEQ   2048
#define HID   16
#define GATES 64   // 4*HID
#define CHUNK 64   // scan: output columns per wave (2 waves/SIMD of TLP)
#define WARM  64   // scan: warmup steps

// ---------------------------------------------------------------------------
// helpers
// ---------------------------------------------------------------------------
__device__ __forceinline__ float lane_bcast(float v, int l) {
  return __int_as_float(__builtin_amdgcn_readlane(__float_as_int(v), l));
}
__device__ __forceinline__ float fast_rcp(float x)  { return __builtin_amdgcn_rcpf(x); }
__device__ __forceinline__ float fast_exp2(float x) { return __builtin_amdgcn_exp2f(x); }

template <int CTRL>
__device__ __forceinline__ float quad_bcast(float v) {
  return __int_as_float(
      __builtin_amdgcn_update_dpp(0, __float_as_int(v), CTRL, 0xF, 0xF, true));
}

#define LOG2E 1.4426950408889634f

// ---------------------------------------------------------------------------
// kernel 0: transpose Wih0 (64x256) -> WT (256x64): weight rows become
// wave-uniform float4 s_load groups in the GEMM.
// ---------------------------------------------------------------------------
__global__ void transpose_w(const float* __restrict__ W, float* __restrict__ WT) {
  int i = blockIdx.x * 256 + threadIdx.x;
  int g = i >> 8;
  int d = i & 255;
  WT[d * GATES + g] = W[i];
}

// ---------------------------------------------------------------------------
// kernel 1: xgT[b][row(g)][t] = nA(g) * (sum_d x[b][d][t]*Wih0[g][d] + bias)
// row(g) = 4*(g&15) + (g>>4); nA = -log2e (or -2log2e for tanh gate).
//
// Cross-round diagnosis: all LDS-tiled variants pin at VALUBusy 35-39% --
// the per-CU LDS pipe is ~2x oversubscribed at this arithmetic intensity
// (3 LDS instrs per 8 FMA instrs); elapsed ~ LDS demand.  The scalar-path
// variant (round 1, zero LDS) also hit 86us, limited by scalar-cache
// thrash: 4 waves x 4 DIFFERENT 16KB gate-quarter slices per block = 64KB
// through a ~16KB sK$.  This version removes the thrash instead of moving
// the traffic: gq = blockIdx.x & 3 with XCD = bid%8 (m09 round-robin) =>
// every block resident on a given CU/XCD uses the SAME quarter -> one
// 16KB slice, sK$-resident, L2-slice-resident.  Block = 4 waves, all gq,
// 256 t; 2048 blocks = 8/CU = 32 waves/CU TLP; ~40 VGPR; ZERO LDS instrs.
// Weights via wave-uniform s_load float4 (free of the vector pipes);
// x via lane-contiguous 256B global loads, prefetched one 4-d group ahead.
// d-accumulation order unchanged (bitwise-same absmax).
// ---------------------------------------------------------------------------
__global__ __launch_bounds__(256, 8) void xg_gemm(
    const float* __restrict__ x, const float* __restrict__ WT,
    const float* __restrict__ bih0, const float* __restrict__ bhh0,
    float* __restrict__ xgT) {
  const int gq = blockIdx.x & 3;       // quarter: constant per XCD (bid%8)
  const int b  = blockIdx.x >> 2;
  const int wave = threadIdx.x >> 6;
  const int lane = threadIdx.x & 63;
  const int t  = blockIdx.y * 256 + wave * 64 + lane;   // 1 t per thread
  const float nA = (gq == 2) ? -2.f * LOG2E : -LOG2E;

  const float* xp = x + (size_t)b * FD * SEQ + t;
  const float* wp = WT + gq * 16;                        // wave-uniform

  float acc[16];
#pragma unroll
  for (int k = 0; k < 16; k++) acc[k] = 0.f;

  float xc[4], xn[4];
#pragma unroll
  for (int u = 0; u < 4; u++) xc[u] = xp[(size_t)u * SEQ];

  for (int d = 0; d < FD; d += 4) {
    // prefetch next group's x (wraps to row 0 on the last group; discarded)
    const int dn = (d + 4 < FD) ? d + 4 : 0;
#pragma unroll
    for (int u = 0; u < 4; u++) xn[u] = xp[(size_t)(dn + u) * SEQ];

#pragma unroll
    for (int u = 0; u < 4; u++) {
      const float4* w4 = (const float4*)(wp + (d + u) * GATES);  // s_load x4
      float4 wa = w4[0], wb = w4[1], wc = w4[2], wd = w4[3];
      float w[16] = {wa.x,wa.y,wa.z,wa.w, wb.x,wb.y,wb.z,wb.w,
                     wc.x,wc.y,wc.z,wc.w, wd.x,wd.y,wd.z,wd.w};
#pragma unroll
      for (int k = 0; k < 16; k++)
        acc[k] = fmaf(xc[u], w[k], acc[k]);
    }
#pragma unroll
    for (int u = 0; u < 4; u++) xc[u] = xn[u];
  }

#pragma unroll
  for (int k = 0; k < 16; k++) {
    int g = gq * 16 + k;                      // torch gate index
    int row = 4 * k + gq;                     // scan lane order
    float bias = bih0[g] + bhh0[g];
    xgT[((size_t)b * GATES + row) * SEQ + t] = (acc[k] + bias) * nA;
  }
}

// ---------------------------------------------------------------------------
// kernel 2: chunk-parallel 2-layer LSTM scan. One wave per (batch, chunk).
// waves_per_eu(2,2) pins 256-VGPR budget (round-8: allocator budgeted for
// unreachable occupancy and spilled ~12 regs onto the recurrence path).
// CHUNK=64/WARM=64: 2 waves/SIMD of TLP.  UNCHANGED from round 11.
// ---------------------------------------------------------------------------
__global__ __launch_bounds__(64) __attribute__((amdgpu_waves_per_eu(2, 2)))
void lstm_scan(
    const float* __restrict__ xgT,
    const float* __restrict__ Whh0,
    const float* __restrict__ Wih1,
    const float* __restrict__ Whh1,
    const float* __restrict__ bih1,
    const float* __restrict__ bhh1,
    float* __restrict__ h2buf) {
  const int b    = blockIdx.x;
  const int t0   = blockIdx.y * CHUNK;
  const int tstart = (t0 >= WARM) ? t0 - WARM : 0;
  const int tend   = t0 + CHUNK;
  const int lane = threadIdx.x;
  const int j    = lane >> 2;          // unit
  const int q    = lane & 3;           // 0 i, 1 f, 2 g(tanh), 3 o
  const int tg   = q * 16 + j;         // torch gate row
  const float nA = (q == 2) ? -2.f * LOG2E : -LOG2E;
  const float sB = (q == 2) ?  2.f :  1.f;
  const float sC = (q == 2) ? -1.f :  0.f;

  float w0[16], wi1[16], w1[16];
  {
    const float4* p = (const float4*)(Whh0 + tg * HID);
#pragma unroll
    for (int m = 0; m < 4; m++) { float4 v = p[m];
      w0[4*m]=v.x*nA; w0[4*m+1]=v.y*nA; w0[4*m+2]=v.z*nA; w0[4*m+3]=v.w*nA; }
    p = (const float4*)(Wih1 + tg * HID);
#pragma unroll
    for (int m = 0; m < 4; m++) { float4 v = p[m];
      wi1[4*m]=v.x*nA; wi1[4*m+1]=v.y*nA; wi1[4*m+2]=v.z*nA; wi1[4*m+3]=v.w*nA; }
    p = (const float4*)(Whh1 + tg * HID);
#pragma unroll
    for (int m = 0; m < 4; m++) { float4 v = p[m];
      w1[4*m]=v.x*nA; w1[4*m+1]=v.y*nA; w1[4*m+2]=v.z*nA; w1[4*m+3]=v.w*nA; }
  }
  const float bias1 = (bih1[tg] + bhh1[tg]) * nA;

  float h1 = 0.f, c1 = 0.f, h2 = 0.f, c2 = 0.f;

  const float* xp = xgT + ((size_t)b * GATES + lane) * SEQ;
  float* hrow = h2buf + ((size_t)b * HID + j) * SEQ;

  auto act = [&](float pre) {          // pre already scaled by nA
    float e = fast_exp2(pre);
    return fmaf(sB, fast_rcp(1.f + e), sC);
  };
  auto tanh_c = [&](float c) {
    float e = fast_exp2(c * (-2.f * LOG2E));
    return fmaf(2.f, fast_rcp(1.f + e), -1.f);
  };

  auto step = [&](float xg, bool doB, int tstore) {
    float s1[16];
#pragma unroll
    for (int m = 0; m < 16; m++) s1[m] = lane_bcast(h1, 4 * m);

    // ---- A: layer-0 dot ----
    float p0 = xg, p1 = 0.f, p2 = 0.f, p3 = 0.f;
#pragma unroll
    for (int m = 0; m < 16; m += 4) {
      p0 = fmaf(s1[m],     w0[m],     p0);
      p1 = fmaf(s1[m + 1], w0[m + 1], p1);
      p2 = fmaf(s1[m + 2], w0[m + 2], p2);
      p3 = fmaf(s1[m + 3], w0[m + 3], p3);
    }
    float preA = (p0 + p1) + (p2 + p3);

    // ---- B: layer-1 dot (pipelined one step behind) ----
    float preB = 0.f;
    if (doB) {
      float r0 = bias1, r1 = 0.f, r2 = 0.f, r3 = 0.f;
#pragma unroll
      for (int m = 0; m < 16; m += 4) {
        r0 = fmaf(s1[m],     wi1[m],     r0);
        r1 = fmaf(s1[m + 1], wi1[m + 1], r1);
        r2 = fmaf(s1[m + 2], wi1[m + 2], r2);
        r3 = fmaf(s1[m + 3], wi1[m + 3], r3);
      }
      float s2[16];
#pragma unroll
      for (int m = 0; m < 16; m++) s2[m] = lane_bcast(h2, 4 * m);
#pragma unroll
      for (int m = 0; m < 16; m += 4) {
        r0 = fmaf(s2[m],     w1[m],     r0);
        r1 = fmaf(s2[m + 1], w1[m + 1], r1);
        r2 = fmaf(s2[m + 2], w1[m + 2], r2);
        r3 = fmaf(s2[m + 3], w1[m + 3], r3);
      }
      preB = (r0 + r1) + (r2 + r3);
    }

    float aA = act(preA);
    float aB = doB ? act(preB) : 0.f;

    float iA = quad_bcast<0x00>(aA);
    float fA = quad_bcast<0x55>(aA);
    float gA = quad_bcast<0xAA>(aA);
    float oA = quad_bcast<0xFF>(aA);
    c1 = fmaf(fA, c1, iA * gA);
    h1 = oA * tanh_c(c1);

    if (doB) {
      float iB = quad_bcast<0x00>(aB);
      float fB = quad_bcast<0x55>(aB);
      float gB = quad_bcast<0xAA>(aB);
      float oB = quad_bcast<0xFF>(aB);
      c2 = fmaf(fB, c2, iB * gB);
      h2 = oB * tanh_c(c2);
      if (q == 0 && tstore >= t0) hrow[tstore] = h2;   // fire-and-forget
    }
  };

  float4 xn = *(const float4*)(xp + tstart);
  for (int tb = tstart; tb < tend; tb += 4) {
    float4 xq = xn;
    if (tb + 4 < tend) xn = *(const float4*)(xp + tb + 4);
    step(xq.x, tb > tstart, tb - 1);
    step(xq.y, true, tb);
    step(xq.z, true, tb + 1);
    step(xq.w, true, tb + 2);
  }
  step(0.f, true, tend - 1);     // epilogue: h2(tend-1); A-side result unused
}

// ---------------------------------------------------------------------------
// kernel 3: out[b][t] = mean_j h2buf[b][j][t]
// ---------------------------------------------------------------------------
__global__ __launch_bounds__(256) void reduce_out(
    const float* __restrict__ h2buf, float* __restrict__ out) {
  int i = blockIdx.x * 256 + threadIdx.x;   // 0 .. B*SEQ-1
  int b = i >> 11;
  int t = i & (SEQ - 1);
  const float* p = h2buf + (size_t)b * HID * SEQ + t;
  float s = 0.f;
#pragma unroll
  for (int jj = 0; jj < 16; jj++) s += p[(size_t)jj * SEQ];
  out[i] = s * 0.0625f;
}

// ---------------------------------------------------------------------------
// launcher
// ---------------------------------------------------------------------------
extern "C" void kernel_launch(void* const* d_in, const int* in_sizes, int n_in,
                              void* d_out, int out_size, void* d_ws, size_t ws_size,
                              hipStream_t stream) {
  const float* x    = (const float*)d_in[0];
  const float* Wih0 = (const float*)d_in[1];
  const float* Whh0 = (const float*)d_in[2];
  const float* bih0 = (const float*)d_in[3];
  const float* bhh0 = (const float*)d_in[4];
  const float* Wih1 = (const float*)d_in[5];
  const float* Whh1 = (const float*)d_in[6];
  const float* bih1 = (const float*)d_in[7];
  const float* bhh1 = (const float*)d_in[8];
  float* out = (float*)d_out;

  float* WT  = (float*)d_ws;                       // 64 KB
  float* xgT = (float*)d_ws + FD * GATES;          // 33.5 MB (B,G,T)

  // h2 buffer (8.4 MB): d_ws if big enough, else recycle the x input buffer
  // (fully consumed by xg_gemm before lstm_scan; harness restores d_in
  // before every launch).
  size_t need = ((size_t)FD * GATES + (size_t)BATCH * GATES * SEQ +
                 (size_t)BATCH * HID * SEQ) * sizeof(float);
  float* h2buf = (ws_size >= need)
                   ? xgT + (size_t)BATCH * GATES * SEQ
                   : (float*)d_in[0];

  transpose_w<<<dim3(64), 256, 0, stream>>>(Wih0, WT);
  // grid.x = 256 interleaves (b, gq) so gq == linear_bid & 3: with XCD =
  // bid % 8 round-robin, each XCD hosts exactly one gate quarter.
  xg_gemm<<<dim3(BATCH * 4, SEQ / 256), 256, 0, stream>>>(
      x, WT, bih0, bhh0, xgT);
  lstm_scan<<<dim3(BATCH, SEQ / CHUNK), 64, 0, stream>>>(
      xgT, Whh0, Wih1, Whh1, bih1, bhh1, h2buf);
  reduce_out<<<dim3(BATCH * SEQ / 256), 256, 0, stream>>>(h2buf, out);
}